// Round 3
// baseline (290.037 us; speedup 1.0000x reference)
//
#include <hip/hip_runtime.h>
#include <stdint.h>

#define BATCH 128
#define NN 512
#define BINS 100
#define WORDS 8    // 512 bits / 64
#define WPAD 9     // +1 u64 pad -> benign LDS bank aliasing
#define ECAP 6144  // upper-tri edge capacity; expected ~2615, huge margin

// One block per graph (256 blocks = 1/CU).
// Phase 1: stream 1 MB graph; 16 independent float4 loads hoisted per wave
//          iteration (8 rows x 2 segs) for memory-level parallelism, then
//          ballot-pack into the LDS bitset. Bit->column mapping permuted but
//          consistent: bit L of word m  <->  column j = (m>>2)*256 + 4L + (m&3).
// Phase 2a: compact upper-tri edge list; analytic j>r mask + 64-lane prefix
//           scan -> one LDS atomic per wave-iter (was ~2700 same-address).
// Phase 2b: edge-parallel AND+popcount triangle counting.
// Phase 2c: clustering coeff + LDS histogram.
__global__ __launch_bounds__(1024) void k_cluster_hist(
    const float* __restrict__ adj1, const float* __restrict__ adj2,
    float* __restrict__ hist /* [2*BATCH][BINS] */)
{
    __shared__ unsigned long long bits[NN][WPAD];   // 36,864 B
    __shared__ unsigned int edges[ECAP];            // 24,576 B  (r<<10 | j)
    __shared__ int tri2[NN];                        //  2,048 B
    __shared__ int histI[BINS];
    __shared__ int ecnt;

    const int gb = blockIdx.x;  // 0..255 ; 0..127 -> adj1, 128..255 -> adj2
    const float* __restrict__ g =
        (gb < BATCH ? adj1 : adj2) + (size_t)(gb & (BATCH - 1)) * NN * NN;

    const int tid  = threadIdx.x;
    const int lane = tid & 63;
    const int wave = tid >> 6;  // 0..15

    if (tid < BINS) histI[tid] = 0;
    if (tid < NN)   tri2[tid]  = 0;
    if (tid == 0)   ecnt = 0;

    // ---- Phase 1: pack 512x512 fp32 -> 512x512-bit LDS bitset.
    // Wave owns rows [wave*32, wave*32+32). 8 rows/iter: 16 independent
    // 16B loads in flight before the first ballot (latency hiding).
    for (int r0 = wave * 32; r0 < wave * 32 + 32; r0 += 8) {
        float4 v[16];
        #pragma unroll
        for (int i = 0; i < 8; ++i) {
            const float* rowp = g + (size_t)(r0 + i) * NN + 4 * lane;
            v[2 * i + 0] = *(const float4*)(rowp);
            v[2 * i + 1] = *(const float4*)(rowp + 256);
        }
        #pragma unroll
        for (int i = 0; i < 8; ++i) {
            #pragma unroll
            for (int s = 0; s < 2; ++s) {
                float4 q = v[2 * i + s];
                unsigned long long m0 = __ballot(q.x != 0.0f);
                unsigned long long m1 = __ballot(q.y != 0.0f);
                unsigned long long m2 = __ballot(q.z != 0.0f);
                unsigned long long m3 = __ballot(q.w != 0.0f);
                if (lane == 0) {
                    bits[r0 + i][s * 4 + 0] = m0;
                    bits[r0 + i][s * 4 + 1] = m1;
                    bits[r0 + i][s * 4 + 2] = m2;
                    bits[r0 + i][s * 4 + 3] = m3;
                }
            }
        }
    }
    __syncthreads();

    // ---- Phase 2a: build upper-triangle edge list (j > r), scan-aggregated.
    for (int p = tid; p < NN * WORDS; p += 1024) {
        int r = p >> 3;
        int m = p & 7;
        unsigned long long w = bits[r][m];
        // analytic mask for j > r:  j = jbase + 4L,  keep L with 4L > r - jbase
        int jbase = ((m >> 2) << 8) + (m & 3);
        unsigned long long wm = w;
        int d = r - jbase;
        if (d >= 0) {
            int Lmin = (d >> 2) + 1;
            wm = (Lmin >= 64) ? 0ull : (w & (~0ull << Lmin));
        }
        int cnt = __popcll(wm);

        // 64-lane inclusive scan of cnt
        int x = cnt;
        #pragma unroll
        for (int off = 1; off < 64; off <<= 1) {
            int y = __shfl_up(x, off, 64);
            if (lane >= off) x += y;
        }
        int excl = x - cnt;
        int base = 0;
        if (lane == 63) base = atomicAdd(&ecnt, x);  // x at lane63 = wave total
        base = __shfl(base, 63, 64);

        int idx = base + excl;
        while (wm) {
            int L = __builtin_ctzll(wm);
            wm &= wm - 1;
            int j = jbase + 4 * L;
            if (idx < ECAP) edges[idx] = ((unsigned)r << 10) | (unsigned)j;
            ++idx;
        }
    }
    __syncthreads();

    // ---- Phase 2b: edge-parallel intersection counts.
    const int ne = ecnt < ECAP ? ecnt : ECAP;
    for (int e = tid; e < ne; e += 1024) {
        unsigned ed = edges[e];
        int i = ed >> 10;
        int j = ed & 1023;
        int acc = 0;
        #pragma unroll
        for (int w = 0; w < WORDS; ++w)
            acc += __popcll(bits[i][w] & bits[j][w]);
        atomicAdd(&tri2[i], acc);
        atomicAdd(&tri2[j], acc);
    }
    __syncthreads();

    // ---- Phase 2c: clustering coeff + histogram.
    if (tid < NN) {
        int deg = 0;
        #pragma unroll
        for (int w = 0; w < WORDS; ++w) deg += __popcll(bits[tid][w]);
        float t2    = (float)tri2[tid];
        float degf  = (float)deg;
        float denom = degf * (degf - 1.0f);
        float c = denom > 0.0f ? t2 / denom : 0.0f;  // exact int/int in fp32
        int idx = (int)(c * 100.0f);                  // trunc == astype(int32)
        idx = idx < 0 ? 0 : (idx > BINS - 1 ? BINS - 1 : idx);
        atomicAdd(&histI[idx], 1);
    }
    __syncthreads();

    if (tid < BINS) hist[(size_t)gb * BINS + tid] = (float)histI[tid];
}

// RBF pair kernels: one pair per thread, float4 loads. 192*256 = 49152 = 3*128*128.
__global__ __launch_bounds__(256) void k_mmd_partial(
    const float* __restrict__ hist, float* __restrict__ partials)
{
    int p = blockIdx.x * 256 + threadIdx.x;
    int t   = p >> 14;          // 0:XX 1:YY 2:XY
    int rem = p & 16383;
    int i = rem >> 7;
    int j = rem & 127;
    const float4* x4;
    const float4* y4;
    float w;
    if (t == 0)      { x4 = (const float4*)(hist + (size_t)i * BINS);           y4 = (const float4*)(hist + (size_t)j * BINS);           w =  1.0f; }
    else if (t == 1) { x4 = (const float4*)(hist + (size_t)(BATCH + i) * BINS); y4 = (const float4*)(hist + (size_t)(BATCH + j) * BINS); w =  1.0f; }
    else             { x4 = (const float4*)(hist + (size_t)i * BINS);           y4 = (const float4*)(hist + (size_t)(BATCH + j) * BINS); w = -2.0f; }
    float sq = 0.0f;
    #pragma unroll
    for (int k = 0; k < BINS / 4; ++k) {  // 100 floats = 25 float4 (rows 400B-aligned)
        float4 a = x4[k];
        float4 b = y4[k];
        float d0 = a.x - b.x, d1 = a.y - b.y, d2 = a.z - b.z, d3 = a.w - b.w;
        sq += d0 * d0 + d1 * d1 + d2 * d2 + d3 * d3;
    }
    float local = w * expf(-0.5f * sq);  // sigma=1 -> 1/(2 sigma^2) = 0.5

    __shared__ float red[256];
    red[threadIdx.x] = local;
    __syncthreads();
    for (int s = 128; s >= 1; s >>= 1) {
        if (threadIdx.x < s) red[threadIdx.x] += red[threadIdx.x + s];
        __syncthreads();
    }
    if (threadIdx.x == 0) partials[blockIdx.x] = red[0];
}

__global__ __launch_bounds__(64) void k_mmd_final(
    const float* __restrict__ partials, float* __restrict__ out, int nparts)
{
    int lane = threadIdx.x;
    float v = 0.0f;
    for (int p = lane; p < nparts; p += 64) v += partials[p];
    #pragma unroll
    for (int off = 32; off >= 1; off >>= 1) v += __shfl_xor(v, off, 64);
    if (lane == 0) out[0] = v * (1.0f / (float)(BATCH * BATCH));
}

extern "C" void kernel_launch(void* const* d_in, const int* in_sizes, int n_in,
                              void* d_out, int out_size, void* d_ws, size_t ws_size,
                              hipStream_t stream) {
    const float* a1 = (const float*)d_in[0];
    const float* a2 = (const float*)d_in[1];
    float* hist     = (float*)d_ws;                                   // 2*128*100 floats
    float* partials = (float*)((char*)d_ws + 2 * BATCH * BINS * sizeof(float)); // 192 floats
    float* out      = (float*)d_out;

    hipLaunchKernelGGL(k_cluster_hist, dim3(2 * BATCH), dim3(1024), 0, stream,
                       a1, a2, hist);
    hipLaunchKernelGGL(k_mmd_partial, dim3(192), dim3(256), 0, stream,
                       hist, partials);
    hipLaunchKernelGGL(k_mmd_final, dim3(1), dim3(64), 0, stream,
                       partials, out, 192);
}

// Round 4
// 288.545 us; speedup vs baseline: 1.0052x; 1.0052x over previous
//
#include <hip/hip_runtime.h>
#include <stdint.h>

#define BATCH 128
#define NN 512
#define BINS 100
#define WORDS 8    // 512 bits / 64
#define WPAD 9     // +1 u64 pad -> benign LDS bank aliasing
#define ECAP 6144  // upper-tri edge capacity; expected ~2615, huge margin
#define PACK_BLOCKS 2048

// Bit mapping (both paths): bit L of word m (m = seg*4+q) <-> column
// j = seg*256 + 4L + q = jbase + 4L with jbase = ((m>>2)<<8) + (m&3).

// ---------------- Split path: Kernel A — pack fp32 adjacency -> bitsets ----
// unit = half-row (1KB). 256 graphs * 512 rows * 2 segs = 262144 units.
// Each wave processes 4 units per iteration: 4 independent float4 wave-loads
// issued back-to-back (MLP), then 16 ballots, then 2-lane 16B stores.
// 2048 blocks * 4 waves = 8192 waves -> 32 units/wave, 32 waves/CU.
__global__ __launch_bounds__(256) void k_pack(
    const float* __restrict__ adj1, const float* __restrict__ adj2,
    unsigned long long* __restrict__ bits_g /* [256][512][8] */)
{
    const int lane = threadIdx.x & 63;
    const int wid  = blockIdx.x * (blockDim.x >> 6) + (threadIdx.x >> 6);
    const int nw   = gridDim.x * (blockDim.x >> 6);
    const int NUNIT = 2 * BATCH * NN * 2;  // 262144

    for (int u0 = wid * 4; u0 < NUNIT; u0 += nw * 4) {
        float4 v[4];
        #pragma unroll
        for (int k = 0; k < 4; ++k) {
            int u  = u0 + k;
            int gb = u >> 10;
            int ui = u & 1023;
            int r  = ui >> 1;
            int sg = ui & 1;
            const float* p = (gb < BATCH ? adj1 : adj2)
                           + (size_t)(gb & (BATCH - 1)) * NN * NN
                           + (size_t)r * NN + sg * 256 + 4 * lane;
            v[k] = *(const float4*)p;
        }
        #pragma unroll
        for (int k = 0; k < 4; ++k) {
            int u  = u0 + k;
            int gb = u >> 10;
            int ui = u & 1023;
            int r  = ui >> 1;
            int sg = ui & 1;
            unsigned long long m0 = __ballot(v[k].x != 0.0f);
            unsigned long long m1 = __ballot(v[k].y != 0.0f);
            unsigned long long m2 = __ballot(v[k].z != 0.0f);
            unsigned long long m3 = __ballot(v[k].w != 0.0f);
            unsigned long long* dst =
                bits_g + ((size_t)(gb * NN + r) * WORDS) + sg * 4;
            unsigned long long lo = lane ? m2 : m0;  // wave-uniform values
            unsigned long long hi = lane ? m3 : m1;
            if (lane < 2) {
                ulonglong2 w; w.x = lo; w.y = hi;
                *(ulonglong2*)(dst + 2 * lane) = w;  // 16B store, lanes 0,1
            }
        }
    }
}

// ---------------- Split path: Kernel B — triangles + histogram -------------
__global__ __launch_bounds__(1024) void k_tri_hist(
    const unsigned long long* __restrict__ bits_g,
    float* __restrict__ hist /* [2*BATCH][BINS] */)
{
    __shared__ unsigned long long bits[NN][WPAD];
    __shared__ unsigned int edges[ECAP];
    __shared__ int tri2[NN];
    __shared__ int histI[BINS];
    __shared__ int ecnt;

    const int gb  = blockIdx.x;
    const int tid = threadIdx.x;
    const int lane = tid & 63;
    const unsigned long long* src = bits_g + (size_t)gb * NN * WORDS;

    if (tid < BINS) histI[tid] = 0;
    if (tid < NN)   tri2[tid]  = 0;
    if (tid == 0)   ecnt = 0;

    // Load 32KB bitset, coalesced, into padded LDS layout.
    #pragma unroll
    for (int g = tid; g < NN * WORDS; g += 1024)
        bits[g >> 3][g & 7] = src[g];
    __syncthreads();

    // Phase 2a: upper-tri edge list (j > r), scan-aggregated.
    for (int p = tid; p < NN * WORDS; p += 1024) {
        int r = p >> 3;
        int m = p & 7;
        unsigned long long w = bits[r][m];
        int jbase = ((m >> 2) << 8) + (m & 3);
        unsigned long long wm = w;
        int d = r - jbase;
        if (d >= 0) {
            int Lmin = (d >> 2) + 1;
            wm = (Lmin >= 64) ? 0ull : (w & (~0ull << Lmin));
        }
        int cnt = __popcll(wm);

        int x = cnt;
        #pragma unroll
        for (int off = 1; off < 64; off <<= 1) {
            int y = __shfl_up(x, off, 64);
            if (lane >= off) x += y;
        }
        int excl = x - cnt;
        int base = 0;
        if (lane == 63) base = atomicAdd(&ecnt, x);
        base = __shfl(base, 63, 64);

        int idx = base + excl;
        while (wm) {
            int L = __builtin_ctzll(wm);
            wm &= wm - 1;
            int j = jbase + 4 * L;
            if (idx < ECAP) edges[idx] = ((unsigned)r << 10) | (unsigned)j;
            ++idx;
        }
    }
    __syncthreads();

    // Phase 2b: edge-parallel intersection counts.
    const int ne = ecnt < ECAP ? ecnt : ECAP;
    for (int e = tid; e < ne; e += 1024) {
        unsigned ed = edges[e];
        int i = ed >> 10;
        int j = ed & 1023;
        int acc = 0;
        #pragma unroll
        for (int w = 0; w < WORDS; ++w)
            acc += __popcll(bits[i][w] & bits[j][w]);
        atomicAdd(&tri2[i], acc);
        atomicAdd(&tri2[j], acc);
    }
    __syncthreads();

    // Phase 2c: clustering coeff + histogram.
    if (tid < NN) {
        int deg = 0;
        #pragma unroll
        for (int w = 0; w < WORDS; ++w) deg += __popcll(bits[tid][w]);
        float t2    = (float)tri2[tid];
        float degf  = (float)deg;
        float denom = degf * (degf - 1.0f);
        float c = denom > 0.0f ? t2 / denom : 0.0f;
        int idx = (int)(c * 100.0f);
        idx = idx < 0 ? 0 : (idx > BINS - 1 ? BINS - 1 : idx);
        atomicAdd(&histI[idx], 1);
    }
    __syncthreads();

    if (tid < BINS) hist[(size_t)gb * BINS + tid] = (float)histI[tid];
}

// ---------------- Fallback: single fused kernel (round-3, known-correct) ---
__global__ __launch_bounds__(1024) void k_cluster_hist(
    const float* __restrict__ adj1, const float* __restrict__ adj2,
    float* __restrict__ hist)
{
    __shared__ unsigned long long bits[NN][WPAD];
    __shared__ unsigned int edges[ECAP];
    __shared__ int tri2[NN];
    __shared__ int histI[BINS];
    __shared__ int ecnt;

    const int gb = blockIdx.x;
    const float* __restrict__ g =
        (gb < BATCH ? adj1 : adj2) + (size_t)(gb & (BATCH - 1)) * NN * NN;

    const int tid  = threadIdx.x;
    const int lane = tid & 63;
    const int wave = tid >> 6;

    if (tid < BINS) histI[tid] = 0;
    if (tid < NN)   tri2[tid]  = 0;
    if (tid == 0)   ecnt = 0;

    for (int r0 = wave * 32; r0 < wave * 32 + 32; r0 += 8) {
        float4 v[16];
        #pragma unroll
        for (int i = 0; i < 8; ++i) {
            const float* rowp = g + (size_t)(r0 + i) * NN + 4 * lane;
            v[2 * i + 0] = *(const float4*)(rowp);
            v[2 * i + 1] = *(const float4*)(rowp + 256);
        }
        #pragma unroll
        for (int i = 0; i < 8; ++i) {
            #pragma unroll
            for (int s = 0; s < 2; ++s) {
                float4 q = v[2 * i + s];
                unsigned long long m0 = __ballot(q.x != 0.0f);
                unsigned long long m1 = __ballot(q.y != 0.0f);
                unsigned long long m2 = __ballot(q.z != 0.0f);
                unsigned long long m3 = __ballot(q.w != 0.0f);
                if (lane == 0) {
                    bits[r0 + i][s * 4 + 0] = m0;
                    bits[r0 + i][s * 4 + 1] = m1;
                    bits[r0 + i][s * 4 + 2] = m2;
                    bits[r0 + i][s * 4 + 3] = m3;
                }
            }
        }
    }
    __syncthreads();

    for (int p = tid; p < NN * WORDS; p += 1024) {
        int r = p >> 3;
        int m = p & 7;
        unsigned long long w = bits[r][m];
        int jbase = ((m >> 2) << 8) + (m & 3);
        unsigned long long wm = w;
        int d = r - jbase;
        if (d >= 0) {
            int Lmin = (d >> 2) + 1;
            wm = (Lmin >= 64) ? 0ull : (w & (~0ull << Lmin));
        }
        int cnt = __popcll(wm);
        int x = cnt;
        #pragma unroll
        for (int off = 1; off < 64; off <<= 1) {
            int y = __shfl_up(x, off, 64);
            if (lane >= off) x += y;
        }
        int excl = x - cnt;
        int base = 0;
        if (lane == 63) base = atomicAdd(&ecnt, x);
        base = __shfl(base, 63, 64);
        int idx = base + excl;
        while (wm) {
            int L = __builtin_ctzll(wm);
            wm &= wm - 1;
            int j = jbase + 4 * L;
            if (idx < ECAP) edges[idx] = ((unsigned)r << 10) | (unsigned)j;
            ++idx;
        }
    }
    __syncthreads();

    const int ne = ecnt < ECAP ? ecnt : ECAP;
    for (int e = tid; e < ne; e += 1024) {
        unsigned ed = edges[e];
        int i = ed >> 10;
        int j = ed & 1023;
        int acc = 0;
        #pragma unroll
        for (int w = 0; w < WORDS; ++w)
            acc += __popcll(bits[i][w] & bits[j][w]);
        atomicAdd(&tri2[i], acc);
        atomicAdd(&tri2[j], acc);
    }
    __syncthreads();

    if (tid < NN) {
        int deg = 0;
        #pragma unroll
        for (int w = 0; w < WORDS; ++w) deg += __popcll(bits[tid][w]);
        float t2    = (float)tri2[tid];
        float degf  = (float)deg;
        float denom = degf * (degf - 1.0f);
        float c = denom > 0.0f ? t2 / denom : 0.0f;
        int idx = (int)(c * 100.0f);
        idx = idx < 0 ? 0 : (idx > BINS - 1 ? BINS - 1 : idx);
        atomicAdd(&histI[idx], 1);
    }
    __syncthreads();

    if (tid < BINS) hist[(size_t)gb * BINS + tid] = (float)histI[tid];
}

// ---------------- MMD kernels ----------------------------------------------
__global__ __launch_bounds__(256) void k_mmd_partial(
    const float* __restrict__ hist, float* __restrict__ partials)
{
    int p = blockIdx.x * 256 + threadIdx.x;
    int t   = p >> 14;
    int rem = p & 16383;
    int i = rem >> 7;
    int j = rem & 127;
    const float4* x4;
    const float4* y4;
    float w;
    if (t == 0)      { x4 = (const float4*)(hist + (size_t)i * BINS);           y4 = (const float4*)(hist + (size_t)j * BINS);           w =  1.0f; }
    else if (t == 1) { x4 = (const float4*)(hist + (size_t)(BATCH + i) * BINS); y4 = (const float4*)(hist + (size_t)(BATCH + j) * BINS); w =  1.0f; }
    else             { x4 = (const float4*)(hist + (size_t)i * BINS);           y4 = (const float4*)(hist + (size_t)(BATCH + j) * BINS); w = -2.0f; }
    float sq = 0.0f;
    #pragma unroll
    for (int k = 0; k < BINS / 4; ++k) {
        float4 a = x4[k];
        float4 b = y4[k];
        float d0 = a.x - b.x, d1 = a.y - b.y, d2 = a.z - b.z, d3 = a.w - b.w;
        sq += d0 * d0 + d1 * d1 + d2 * d2 + d3 * d3;
    }
    float local = w * expf(-0.5f * sq);

    __shared__ float red[256];
    red[threadIdx.x] = local;
    __syncthreads();
    for (int s = 128; s >= 1; s >>= 1) {
        if (threadIdx.x < s) red[threadIdx.x] += red[threadIdx.x + s];
        __syncthreads();
    }
    if (threadIdx.x == 0) partials[blockIdx.x] = red[0];
}

__global__ __launch_bounds__(64) void k_mmd_final(
    const float* __restrict__ partials, float* __restrict__ out, int nparts)
{
    int lane = threadIdx.x;
    float v = 0.0f;
    for (int p = lane; p < nparts; p += 64) v += partials[p];
    #pragma unroll
    for (int off = 32; off >= 1; off >>= 1) v += __shfl_xor(v, off, 64);
    if (lane == 0) out[0] = v * (1.0f / (float)(BATCH * BATCH));
}

extern "C" void kernel_launch(void* const* d_in, const int* in_sizes, int n_in,
                              void* d_out, int out_size, void* d_ws, size_t ws_size,
                              hipStream_t stream) {
    const float* a1 = (const float*)d_in[0];
    const float* a2 = (const float*)d_in[1];
    float* out = (float*)d_out;

    const size_t bits_bytes = (size_t)2 * BATCH * NN * WORDS * 8;  // 8 MB
    const size_t hist_bytes = (size_t)2 * BATCH * BINS * 4;        // 102.4 KB
    const size_t need = bits_bytes + hist_bytes + 192 * 4;

    if (ws_size >= need) {
        unsigned long long* bits_g = (unsigned long long*)d_ws;
        float* hist     = (float*)((char*)d_ws + bits_bytes);
        float* partials = (float*)((char*)d_ws + bits_bytes + hist_bytes);
        hipLaunchKernelGGL(k_pack, dim3(PACK_BLOCKS), dim3(256), 0, stream,
                           a1, a2, bits_g);
        hipLaunchKernelGGL(k_tri_hist, dim3(2 * BATCH), dim3(1024), 0, stream,
                           bits_g, hist);
        hipLaunchKernelGGL(k_mmd_partial, dim3(192), dim3(256), 0, stream,
                           hist, partials);
        hipLaunchKernelGGL(k_mmd_final, dim3(1), dim3(64), 0, stream,
                           partials, out, 192);
    } else {
        float* hist     = (float*)d_ws;
        float* partials = (float*)((char*)d_ws + hist_bytes);
        hipLaunchKernelGGL(k_cluster_hist, dim3(2 * BATCH), dim3(1024), 0, stream,
                           a1, a2, hist);
        hipLaunchKernelGGL(k_mmd_partial, dim3(192), dim3(256), 0, stream,
                           hist, partials);
        hipLaunchKernelGGL(k_mmd_final, dim3(1), dim3(64), 0, stream,
                           partials, out, 192);
    }
}